// Round 10
// baseline (399.627 us; speedup 1.0000x reference)
//
#include <hip/hip_runtime.h>
#include <float.h>
#include <math.h>

// NormEMAVectorQuantizer via split-fp16 MFMA + exact fp32 refinement.
// z (8,2048,256) f32, weight (8192,256) f32 (unit rows).
// out = [ z_q (16384*256) | loss (1) | indices (16384, as float) ]
//
// Round-10: coarse GEMM switched bf16 3-term K=768 -> fp16 2-term K=512:
//   A = [zh | zh], B = [wh | wl]  =>  dot' = zh.(wh+wl) = zh.w
//   eps_dot <= |zl.w| + worst-case-flushed |zh.wl| <= 2*2^-11 ~ 9.8e-4
//   eps_d = 2*eps_dot ~ 1.97e-3 -> THR = 4e-3 (= 2*eps_d) flags every row
//   whose argmin could differ; k_refine (exact fp32) resolves those.
// K-loop structure identical to r9 (128x256, BK=32, 8 waves 2Mx4N 64x64,
// triple-buffer 72KB, launch_bounds(512,4), vmcnt(3), LDS-plane epilogue).

#define BT_ 16384
#define D_  256
#define N_  8192
#define BETA_ 1.0f
#define THR_ 4e-3f

#define BM 128
#define BN 256
#define NKT 16           // 512 / 32 K-tiles
#define NTILES 32        // N_ / BN

typedef __attribute__((ext_vector_type(8))) _Float16 f16x8;
typedef __attribute__((ext_vector_type(4))) float f32x4;

__device__ __forceinline__ void gld16(void* lds, const void* g) {
  __builtin_amdgcn_global_load_lds(
      (const __attribute__((address_space(1))) void*)g,
      (__attribute__((address_space(3))) void*)lds, 16, 0, 0);
}

__device__ __forceinline__ unsigned short f2h(float x) {
  _Float16 h = (_Float16)x;
  return __builtin_bit_cast(unsigned short, h);
}
__device__ __forceinline__ float h2f(unsigned short u) {
  return (float)__builtin_bit_cast(_Float16, u);
}

// ---------------- kernel 1: normalize z, store zn + A = [zh|zh] ----------------
__global__ __launch_bounds__(256) void k_prep_z(const float* __restrict__ z,
                                                float* __restrict__ zn,
                                                ushort* __restrict__ Acat) {
  const int row  = blockIdx.x * 4 + (threadIdx.x >> 6);
  const int lane = threadIdx.x & 63;
  float4 v = *(reinterpret_cast<const float4*>(z) + (size_t)row * 64 + lane);
  float s = v.x * v.x + v.y * v.y + v.z * v.z + v.w * v.w;
#pragma unroll
  for (int o = 32; o > 0; o >>= 1) s += __shfl_xor(s, o, 64);
  float dn = fmaxf(sqrtf(s), 1e-12f);
  v.x /= dn; v.y /= dn; v.z /= dn; v.w /= dn;
  *(reinterpret_cast<float4*>(zn) + (size_t)row * 64 + lane) = v;
  ushort4 h = make_ushort4(f2h(v.x), f2h(v.y), f2h(v.z), f2h(v.w));
  ushort4* A4 = reinterpret_cast<ushort4*>(Acat);
  size_t rb = (size_t)row * 128 + lane;   // 512/4 = 128 ushort4 per row
  A4[rb]      = h;    // zh
  A4[rb + 64] = h;    // zh (second copy)
}

// ---------------- kernel 2: wn2, B = [wh | wl] ----------------
__global__ __launch_bounds__(256) void k_prep_w(const float* __restrict__ w,
                                                float* __restrict__ wn2,
                                                ushort* __restrict__ Bcat) {
  const int row  = blockIdx.x * 4 + (threadIdx.x >> 6);
  const int lane = threadIdx.x & 63;
  float4 v = *(reinterpret_cast<const float4*>(w) + (size_t)row * 64 + lane);
  float s = v.x * v.x + v.y * v.y + v.z * v.z + v.w * v.w;
#pragma unroll
  for (int o = 32; o > 0; o >>= 1) s += __shfl_xor(s, o, 64);
  if (lane == 0) wn2[row] = s;
  ushort4 h  = make_ushort4(f2h(v.x), f2h(v.y), f2h(v.z), f2h(v.w));
  ushort4 lo = make_ushort4(f2h(v.x - h2f(h.x)), f2h(v.y - h2f(h.y)),
                            f2h(v.z - h2f(h.z)), f2h(v.w - h2f(h.w)));
  ushort4* B4 = reinterpret_cast<ushort4*>(Bcat);
  size_t rb = (size_t)row * 128 + lane;
  B4[rb]      = h;    // wh
  B4[rb + 64] = lo;   // wl
}

// ---------------- kernel 3: high-occupancy fp16 MFMA GEMM, 128x256, BK=32 ---
// grid = 128 rt x 32 ct = 4096 blocks, 512 threads (8 waves, 2M x 4N,
// 64x64 out each -> acc 64 VGPR). LDS: 3 x 24KB buffers (A 8KB + B 16KB).
// Swizzle (64B rows, 4 x 16B granules): LDS[r][g] = G[r][g ^ ((r>>1)&3)].
__global__ __launch_bounds__(512, 4) void k_coarse(const ushort* __restrict__ Acat,
                                                   const ushort* __restrict__ Bcat,
                                                   const float* __restrict__ wn2,
                                                   float* __restrict__ tm,
                                                   float* __restrict__ ts,
                                                   int* __restrict__ ti) {
  extern __shared__ char smem[];

  const int tid = threadIdx.x;
  const int l   = tid & 63;
  const int wv  = tid >> 6;
  const int wr  = wv >> 2;       // 0..1 -> rows wr*64
  const int wc  = wv & 3;        // 0..3 -> cols wc*64
  // XCD-aware 2D chunking: per XCD 512 blocks, 16 chunks of 32 as 8rt x 4ct
  const int bid  = blockIdx.x;
  const int xcd  = bid & 7;
  const int q    = bid >> 3;               // 0..511
  const int chnk = q >> 5, wq = q & 31;    // 16 chunks of 32
  const int rt   = xcd * 16 + (chnk >> 3) * 8 + (wq >> 2);
  const int ct   = (chnk & 7) * 4 + (wq & 3);
  const int row0 = rt * BM;
  const int col0 = ct * BN;

  // ---- staging setup: 24 x 1KB units/tile (A:0-7, B:8-23), 3 per wave ----
  // unit u covers 16 rows; lane l -> row l>>2, LDS granule l&3,
  // source granule (l&3) ^ ((l>>3)&3)   [= (row>>1)&3 with row=l>>2]
  const int sgr = ((l & 3) ^ ((l >> 3) & 3)) * 16;
  const char* gsrc[3];
  unsigned    ldst[3];
#pragma unroll
  for (int s = 0; s < 3; ++s) {
    int u = wv * 3 + s;
    if (u < 8) {
      gsrc[s] = (const char*)Acat + (size_t)(row0 + u * 16 + (l >> 2)) * 1024 + sgr;
      ldst[s] = u * 1024;
    } else {
      gsrc[s] = (const char*)Bcat + (size_t)(col0 + (u - 8) * 16 + (l >> 2)) * 1024 + sgr;
      ldst[s] = 8192 + (u - 8) * 1024;
    }
  }
#define STAGE(t)                                                               \
  do {                                                                         \
    char* _b = smem + ((t) % 3) * 24576;                                       \
    _Pragma("unroll")                                                          \
    for (int s = 0; s < 3; ++s) gld16(_b + ldst[s], gsrc[s] + (size_t)(t) * 64); \
  } while (0)

  // ---- fragment read offsets ----
  const int lA  = l & 15;
  const int gsw = (lA >> 1) & 3;                      // (row>>1)&3
  const int gk  = (l >> 4) ^ gsw;                     // swizzled granule
  const unsigned aOff = (unsigned)((wr * 64 + lA) * 64 + gk * 16);
  const unsigned bOff = (unsigned)(8192 + (wc * 64 + lA) * 64 + gk * 16);

  f32x4 acc[4][4];
#pragma unroll
  for (int i = 0; i < 4; ++i)
#pragma unroll
    for (int j = 0; j < 4; ++j) acc[i][j] = (f32x4){0.f, 0.f, 0.f, 0.f};

  // prologue: stage tiles 0,1
  STAGE(0);
  STAGE(1);

  for (int t = 0; t < NKT; ++t) {
    char* buf = smem + (t % 3) * 24576;
    // oldest 3 outstanding loads = stage(t), issued 2 tiles ago.
    if (t < NKT - 1) asm volatile("s_waitcnt vmcnt(3)" ::: "memory");
    else             asm volatile("s_waitcnt vmcnt(0)" ::: "memory");
    __builtin_amdgcn_s_barrier();
    __builtin_amdgcn_sched_barrier(0);
    if (t + 2 < NKT) STAGE(t + 2);   // writes buf (t+2)%3 == (t-1)%3: free

    f16x8 af[4], bg[4];
#pragma unroll
    for (int i = 0; i < 4; ++i)
      af[i] = *(const f16x8*)(buf + aOff + i * 1024);
#pragma unroll
    for (int j = 0; j < 4; ++j)
      bg[j] = *(const f16x8*)(buf + bOff + j * 1024);
    __builtin_amdgcn_s_setprio(1);
#pragma unroll
    for (int i = 0; i < 4; ++i)
#pragma unroll
      for (int j = 0; j < 4; ++j)
        acc[i][j] = __builtin_amdgcn_mfma_f32_16x16x32_f16(af[i], bg[j], acc[i][j], 0, 0, 0);
    __builtin_amdgcn_s_setprio(0);
  }
#undef STAGE

  // -------- epilogue: j-min -> one shfl_xor(8) -> LDS planes -> scan -------
  float wnv[4];
#pragma unroll
  for (int n = 0; n < 4; ++n) wnv[n] = wn2[col0 + wc * 64 + n * 16 + lA];
  float* pm = (float*)smem;
  float* ps = (float*)(smem + 16896);
  int*   pc = (int*)(smem + 33792);
  __syncthreads();   // all K-loop LDS reads complete before reuse

#pragma unroll
  for (int i = 0; i < 4; ++i) {
#pragma unroll
    for (int qq = 0; qq < 4; ++qq) {
      float m = FLT_MAX, s = FLT_MAX; int c = 0;
#pragma unroll
      for (int j = 0; j < 4; ++j) {
        float d = fmaf(-2.0f, acc[i][j][qq], wnv[j]);
        int cc = wc * 64 + j * 16 + lA;
        if (d < m) { s = m; m = d; c = cc; }
        else if (d < s) s = d;
      }
      // one merge round across lane^8 (lA and lA+8 hold disjoint cols)
      float om = __shfl_xor(m, 8, 64);
      float os = __shfl_xor(s, 8, 64);
      int   oc = __shfl_xor(c, 8, 64);
      float ns = fminf(fminf(s, os), fmaxf(m, om));
      if (om < m || (om == m && oc < c)) { m = om; c = oc; }
      s = ns;
      if ((l & 8) == 0) {
        int row = wr * 64 + i * 16 + (l >> 4) * 4 + qq;
        int w33 = row * 33 + wc * 8 + (l & 7);
        pm[w33] = m; ps[w33] = s; pc[w33] = c;
      }
    }
  }
  __syncthreads();
  {
    const int row = tid >> 2;      // 0..127
    const int qd  = tid & 3;       // quarter: 8 slots each
    float gm = FLT_MAX, gs = FLT_MAX; int gc = 0x7fffffff;
#pragma unroll
    for (int k = 0; k < 8; ++k) {
      int w33 = row * 33 + qd * 8 + k;
      float m = pm[w33], s = ps[w33]; int c = pc[w33];
      float ns = fminf(fminf(gs, s), fmaxf(gm, m));
      if (m < gm || (m == gm && c < gc)) { gm = m; gc = c; }
      gs = ns;
    }
#pragma unroll
    for (int msk = 1; msk <= 2; msk <<= 1) {
      float om = __shfl_xor(gm, msk, 64);
      float os = __shfl_xor(gs, msk, 64);
      int   oc = __shfl_xor(gc, msk, 64);
      float ns = fminf(fminf(gs, os), fmaxf(gm, om));
      if (om < gm || (om == gm && oc < gc)) { gm = om; gc = oc; }
      gs = ns;
    }
    if (qd == 0) {
      size_t o = (size_t)ct * BT_ + row0 + row;
      tm[o] = gm; ts[o] = gs; ti[o] = col0 + gc;
    }
  }
}

// ---------------- kernel 4: combine tiles per row, flag ambiguous ----------------
__global__ __launch_bounds__(256) void k_combine(const float* __restrict__ tm,
                                                 const float* __restrict__ ts,
                                                 const int* __restrict__ ti,
                                                 int* __restrict__ idxf,
                                                 int* __restrict__ flagged,
                                                 int* __restrict__ count) {
  const int row = blockIdx.x * 256 + threadIdx.x;
  float m = FLT_MAX, s = FLT_MAX; int bi = 0x7fffffff;
  for (int t = 0; t < NTILES; ++t) {
    size_t o = (size_t)t * BT_ + row;
    float om = tm[o], os = ts[o]; int oi = ti[o];
    float nsv = fminf(fminf(s, os), fmaxf(m, om));
    if (om < m || (om == m && oi < bi)) { m = om; bi = oi; }
    s = nsv;
  }
  idxf[row] = bi;
  if (s - m <= THR_) {
    int p = atomicAdd(count, 1);
    flagged[p] = row;
  }
}

// ---------------- kernel 5: exact fp32 refinement of flagged rows ----------------
__global__ __launch_bounds__(128) void k_refine(const float* __restrict__ zn,
                                                const float* __restrict__ w,
                                                const float* __restrict__ wn2,
                                                const float* __restrict__ tm,
                                                const int* __restrict__ flagged,
                                                const int* __restrict__ count,
                                                int* __restrict__ idxf) {
  __shared__ float4 znr[64];
  __shared__ float tmr[32];
  __shared__ float m1s;
  __shared__ float wd[2];
  __shared__ int   wi[2];
  const int tid = threadIdx.x;
  const int cnt = *count;
  for (int f = blockIdx.x; f < cnt; f += gridDim.x) {
    __syncthreads();   // protect LDS reuse across iterations
    const int row = flagged[f];
    if (tid < 64) {
      znr[tid] = *(reinterpret_cast<const float4*>(zn) + (size_t)row * 64 + tid);
    }
    if (tid < 32) {
      float tv = tm[(size_t)tid * BT_ + row];
      tmr[tid] = tv;
      float mm = tv;
#pragma unroll
      for (int msk = 16; msk > 0; msk >>= 1) mm = fminf(mm, __shfl_xor(mm, msk, 64));
      if (tid == 0) m1s = mm;
    }
    __syncthreads();
    const float lim = m1s + THR_;
    float bd = FLT_MAX; int bi = 0x7fffffff;
    for (int t = 0; t < NTILES; ++t) {
      if (tmr[t] <= lim) {
#pragma unroll
        for (int h = 0; h < 2; ++h) {
          int c = t * BN + h * 128 + tid;
          const float4* wr4 = reinterpret_cast<const float4*>(w) + (size_t)c * 64;
          float d0 = 0.f, d1 = 0.f, d2 = 0.f, d3 = 0.f;
#pragma unroll
          for (int k4 = 0; k4 < 16; ++k4) {
            float4 a0 = znr[k4 * 4 + 0], b0 = wr4[k4 * 4 + 0];
            float4 a1 = znr[k4 * 4 + 1], b1 = wr4[k4 * 4 + 1];
            float4 a2 = znr[k4 * 4 + 2], b2 = wr4[k4 * 4 + 2];
            float4 a3 = znr[k4 * 4 + 3], b3 = wr4[k4 * 4 + 3];
            d0 = fmaf(a0.x, b0.x, d0); d0 = fmaf(a0.y, b0.y, d0);
            d0 = fmaf(a0.z, b0.z, d0); d0 = fmaf(a0.w, b0.w, d0);
            d1 = fmaf(a1.x, b1.x, d1); d1 = fmaf(a1.y, b1.y, d1);
            d1 = fmaf(a1.z, b1.z, d1); d1 = fmaf(a1.w, b1.w, d1);
            d2 = fmaf(a2.x, b2.x, d2); d2 = fmaf(a2.y, b2.y, d2);
            d2 = fmaf(a2.z, b2.z, d2); d2 = fmaf(a2.w, b2.w, d2);
            d3 = fmaf(a3.x, b3.x, d3); d3 = fmaf(a3.y, b3.y, d3);
            d3 = fmaf(a3.z, b3.z, d3); d3 = fmaf(a3.w, b3.w, d3);
          }
          float dot = (d0 + d1) + (d2 + d3);
          float d = fmaf(-2.0f, dot, wn2[c]);
          if (d < bd || (d == bd && c < bi)) { bd = d; bi = c; }
        }
      }
    }
#pragma unroll
    for (int msk = 1; msk < 64; msk <<= 1) {
      float od = __shfl_xor(bd, msk, 64);
      int   oi = __shfl_xor(bi, msk, 64);
      if (od < bd || (od == bd && oi < bi)) { bd = od; bi = oi; }
    }
    if ((tid & 63) == 0) { wd[tid >> 6] = bd; wi[tid >> 6] = bi; }
    __syncthreads();
    if (tid == 0) {
      float fd = wd[0]; int fi = wi[0];
      if (wd[1] < fd || (wd[1] == fd && wi[1] < fi)) { fd = wd[1]; fi = wi[1]; }
      idxf[row] = fi;
    }
  }
}

// ---------------- kernel 6: gather + loss partials (atomic-free) ----------------
__global__ __launch_bounds__(256) void k_gather(const float* __restrict__ zn,
                                                const float* __restrict__ w,
                                                const int* __restrict__ idxf,
                                                float* __restrict__ zq,
                                                float* __restrict__ idx_out,
                                                float* __restrict__ wpart) {
  const int row  = blockIdx.x * 4 + (threadIdx.x >> 6);
  const int lane = threadIdx.x & 63;
  const int bi = idxf[row];
  float4 cv = *(reinterpret_cast<const float4*>(w)  + (size_t)bi  * 64 + lane);
  float4 zv = *(reinterpret_cast<const float4*>(zn) + (size_t)row * 64 + lane);
  *(reinterpret_cast<float4*>(zq) + (size_t)row * 64 + lane) = cv;
  float dx = cv.x - zv.x, dy = cv.y - zv.y, dz = cv.z - zv.z, dw = cv.w - zv.w;
  float s = dx * dx + dy * dy + dz * dz + dw * dw;
#pragma unroll
  for (int o = 32; o > 0; o >>= 1) s += __shfl_xor(s, o, 64);
  if (lane == 0) {
    wpart[row] = s;
    idx_out[row] = (float)bi;
  }
}

// ---------------- kernel 7: final loss reduction ----------------
__global__ __launch_bounds__(256) void k_final(const float* __restrict__ wpart,
                                               float* __restrict__ loss_out) {
  __shared__ float wsum[4];
  float s = 0.f;
  for (int i = threadIdx.x; i < BT_; i += 256) s += wpart[i];
#pragma unroll
  for (int o = 32; o > 0; o >>= 1) s += __shfl_xor(s, o, 64);
  if ((threadIdx.x & 63) == 0) wsum[threadIdx.x >> 6] = s;
  __syncthreads();
  if (threadIdx.x == 0)
    loss_out[0] = BETA_ * ((wsum[0] + wsum[1]) + (wsum[2] + wsum[3])) *
                  (1.0f / (float)(BT_ * D_));
}

extern "C" void kernel_launch(void* const* d_in, const int* in_sizes, int n_in,
                              void* d_out, int out_size, void* d_ws, size_t ws_size,
                              hipStream_t stream) {
  const float* z = (const float*)d_in[0];
  const float* w = (const float*)d_in[1];

  float* out      = (float*)d_out;
  float* zq       = out;
  float* loss_out = out + (size_t)BT_ * D_;
  float* idx_out  = loss_out + 1;

  char* wsb = (char*)d_ws;
  float*  zn      = (float*)(wsb);                         // 16 MB
  ushort* Acat    = (ushort*)(wsb + 16777216);             // 16 MB (BT*512*2B)
  ushort* Bcat    = (ushort*)(wsb + 33554432);             // 8 MB  (N*512*2B)
  float*  tm      = (float*)(wsb + 41943040);              // 2 MB used
  float*  ts      = (float*)(wsb + 46137344);              // 2 MB used (reused as wpart)
  int*    ti      = (int*)(wsb + 50331648);                // 2 MB used
  float*  wn2     = (float*)(wsb + 54525952);              // 32 KB
  int*    idxf    = (int*)(wsb + 54558720);                // 64 KB
  int*    flagged = (int*)(wsb + 54624256);                // 64 KB
  int*    count   = (int*)(wsb + 54689792);
  float*  wpart   = ts;   // ts is dead after k_combine

  hipFuncSetAttribute((const void*)k_coarse,
                      hipFuncAttributeMaxDynamicSharedMemorySize, 73728);

  hipMemsetAsync(count, 0, 4, stream);
  k_prep_z<<<BT_ / 4, 256, 0, stream>>>(z, zn, Acat);
  k_prep_w<<<N_ / 4, 256, 0, stream>>>(w, wn2, Bcat);
  k_coarse<<<(BT_ / BM) * NTILES, 512, 73728, stream>>>(Acat, Bcat, wn2, tm, ts, ti);
  k_combine<<<BT_ / 256, 256, 0, stream>>>(tm, ts, ti, idxf, flagged, count);
  k_refine<<<2048, 128, 0, stream>>>(zn, w, wn2, tm, flagged, count, idxf);
  k_gather<<<BT_ / 4, 256, 0, stream>>>(zn, w, idxf, zq, idx_out, wpart);
  k_final<<<1, 256, 0, stream>>>(wpart, loss_out);
}

// Round 11
// 347.262 us; speedup vs baseline: 1.1508x; 1.1508x over previous
//
#include <hip/hip_runtime.h>
#include <float.h>
#include <math.h>

// NormEMAVectorQuantizer via split-fp16 MFMA + exact fp32 refinement.
// z (8,2048,256) f32, weight (8192,256) f32 (unit rows).
// out = [ z_q (16384*256) | loss (1) | indices (16384, as float) ]
//
// Round-11: refine rebuilt after r10's 200us/222MB-FETCH blowup.
//  - per-row threshold THR_row = 2*(||zn-fp16(zn)|| + max_c||w-fp16(w)||)+1e-4
//    (rigorous coarse-error bound; ~8.6e-4 vs r10's global 4e-3)
//  - tile-binned refine: flagged rows appended to per-tile lists; one
//    thread = one code of the tile (w row L2-resident across rows);
//    exact fp32 distance -> wave-min -> atomicMin on (ord(d)<<32|idx).
// k_coarse unchanged from r10 (fp16 2-term K=512, 128x256, 8 waves, occ-4).

#define BT_ 16384
#define D_  256
#define N_  8192
#define BETA_ 1.0f

#define BM 128
#define BN 256
#define NKT 16           // 512 / 32 K-tiles
#define NTILES 32        // N_ / BN

typedef __attribute__((ext_vector_type(8))) _Float16 f16x8;
typedef __attribute__((ext_vector_type(4))) float f32x4;

__device__ __forceinline__ void gld16(void* lds, const void* g) {
  __builtin_amdgcn_global_load_lds(
      (const __attribute__((address_space(1))) void*)g,
      (__attribute__((address_space(3))) void*)lds, 16, 0, 0);
}

__device__ __forceinline__ unsigned short f2h(float x) {
  _Float16 h = (_Float16)x;
  return __builtin_bit_cast(unsigned short, h);
}
__device__ __forceinline__ float h2f(unsigned short u) {
  return (float)__builtin_bit_cast(_Float16, u);
}
// monotone float -> uint32 (total order, handles negatives exactly)
__device__ __forceinline__ unsigned ford(float f) {
  unsigned b = __float_as_uint(f);
  return (b & 0x80000000u) ? ~b : (b | 0x80000000u);
}

// ---------------- kernel 1: normalize z, A = [zh|zh], rl = ||zl|| ------------
__global__ __launch_bounds__(256) void k_prep_z(const float* __restrict__ z,
                                                float* __restrict__ zn,
                                                ushort* __restrict__ Acat,
                                                float* __restrict__ rl) {
  const int row  = blockIdx.x * 4 + (threadIdx.x >> 6);
  const int lane = threadIdx.x & 63;
  float4 v = *(reinterpret_cast<const float4*>(z) + (size_t)row * 64 + lane);
  float s = v.x * v.x + v.y * v.y + v.z * v.z + v.w * v.w;
#pragma unroll
  for (int o = 32; o > 0; o >>= 1) s += __shfl_xor(s, o, 64);
  float dn = fmaxf(sqrtf(s), 1e-12f);
  v.x /= dn; v.y /= dn; v.z /= dn; v.w /= dn;
  *(reinterpret_cast<float4*>(zn) + (size_t)row * 64 + lane) = v;
  ushort4 h = make_ushort4(f2h(v.x), f2h(v.y), f2h(v.z), f2h(v.w));
  float lx = v.x - h2f(h.x), ly = v.y - h2f(h.y);
  float lz = v.z - h2f(h.z), lw = v.w - h2f(h.w);
  float s2 = lx * lx + ly * ly + lz * lz + lw * lw;
#pragma unroll
  for (int o = 32; o > 0; o >>= 1) s2 += __shfl_xor(s2, o, 64);
  if (lane == 0) rl[row] = sqrtf(s2);
  ushort4* A4 = reinterpret_cast<ushort4*>(Acat);
  size_t rb = (size_t)row * 128 + lane;   // 512/4 = 128 ushort4 per row
  A4[rb]      = h;    // zh
  A4[rb + 64] = h;    // zh (second copy)
}

// ---------------- kernel 2: wn2, B = [wh|wl], wlmax = max ||wl|| -------------
__global__ __launch_bounds__(256) void k_prep_w(const float* __restrict__ w,
                                                float* __restrict__ wn2,
                                                ushort* __restrict__ Bcat,
                                                int* __restrict__ wlmax) {
  const int row  = blockIdx.x * 4 + (threadIdx.x >> 6);
  const int lane = threadIdx.x & 63;
  float4 v = *(reinterpret_cast<const float4*>(w) + (size_t)row * 64 + lane);
  float s = v.x * v.x + v.y * v.y + v.z * v.z + v.w * v.w;
#pragma unroll
  for (int o = 32; o > 0; o >>= 1) s += __shfl_xor(s, o, 64);
  if (lane == 0) wn2[row] = s;
  ushort4 h  = make_ushort4(f2h(v.x), f2h(v.y), f2h(v.z), f2h(v.w));
  float lx = v.x - h2f(h.x), ly = v.y - h2f(h.y);
  float lz = v.z - h2f(h.z), lw = v.w - h2f(h.w);
  ushort4 lo = make_ushort4(f2h(lx), f2h(ly), f2h(lz), f2h(lw));
  float s2 = lx * lx + ly * ly + lz * lz + lw * lw;
#pragma unroll
  for (int o = 32; o > 0; o >>= 1) s2 += __shfl_xor(s2, o, 64);
  if (lane == 0) atomicMax(wlmax, __float_as_int(sqrtf(s2)));  // positive floats
  ushort4* B4 = reinterpret_cast<ushort4*>(Bcat);
  size_t rb = (size_t)row * 128 + lane;
  B4[rb]      = h;    // wh
  B4[rb + 64] = lo;   // wl
}

// ---------------- kernel 3: high-occupancy fp16 MFMA GEMM (r10, unchanged) --
__global__ __launch_bounds__(512, 4) void k_coarse(const ushort* __restrict__ Acat,
                                                   const ushort* __restrict__ Bcat,
                                                   const float* __restrict__ wn2,
                                                   float* __restrict__ tm,
                                                   float* __restrict__ ts,
                                                   int* __restrict__ ti) {
  extern __shared__ char smem[];

  const int tid = threadIdx.x;
  const int l   = tid & 63;
  const int wv  = tid >> 6;
  const int wr  = wv >> 2;       // 0..1 -> rows wr*64
  const int wc  = wv & 3;        // 0..3 -> cols wc*64
  const int bid  = blockIdx.x;
  const int xcd  = bid & 7;
  const int q    = bid >> 3;               // 0..511
  const int chnk = q >> 5, wq = q & 31;    // 16 chunks of 32
  const int rt   = xcd * 16 + (chnk >> 3) * 8 + (wq >> 2);
  const int ct   = (chnk & 7) * 4 + (wq & 3);
  const int row0 = rt * BM;
  const int col0 = ct * BN;

  const int sgr = ((l & 3) ^ ((l >> 3) & 3)) * 16;
  const char* gsrc[3];
  unsigned    ldst[3];
#pragma unroll
  for (int s = 0; s < 3; ++s) {
    int u = wv * 3 + s;
    if (u < 8) {
      gsrc[s] = (const char*)Acat + (size_t)(row0 + u * 16 + (l >> 2)) * 1024 + sgr;
      ldst[s] = u * 1024;
    } else {
      gsrc[s] = (const char*)Bcat + (size_t)(col0 + (u - 8) * 16 + (l >> 2)) * 1024 + sgr;
      ldst[s] = 8192 + (u - 8) * 1024;
    }
  }
#define STAGE(t)                                                               \
  do {                                                                         \
    char* _b = smem + ((t) % 3) * 24576;                                       \
    _Pragma("unroll")                                                          \
    for (int s = 0; s < 3; ++s) gld16(_b + ldst[s], gsrc[s] + (size_t)(t) * 64); \
  } while (0)

  const int lA  = l & 15;
  const int gsw = (lA >> 1) & 3;
  const int gk  = (l >> 4) ^ gsw;
  const unsigned aOff = (unsigned)((wr * 64 + lA) * 64 + gk * 16);
  const unsigned bOff = (unsigned)(8192 + (wc * 64 + lA) * 64 + gk * 16);

  f32x4 acc[4][4];
#pragma unroll
  for (int i = 0; i < 4; ++i)
#pragma unroll
    for (int j = 0; j < 4; ++j) acc[i][j] = (f32x4){0.f, 0.f, 0.f, 0.f};

  STAGE(0);
  STAGE(1);

  for (int t = 0; t < NKT; ++t) {
    char* buf = smem + (t % 3) * 24576;
    if (t < NKT - 1) asm volatile("s_waitcnt vmcnt(3)" ::: "memory");
    else             asm volatile("s_waitcnt vmcnt(0)" ::: "memory");
    __builtin_amdgcn_s_barrier();
    __builtin_amdgcn_sched_barrier(0);
    if (t + 2 < NKT) STAGE(t + 2);

    f16x8 af[4], bg[4];
#pragma unroll
    for (int i = 0; i < 4; ++i)
      af[i] = *(const f16x8*)(buf + aOff + i * 1024);
#pragma unroll
    for (int j = 0; j < 4; ++j)
      bg[j] = *(const f16x8*)(buf + bOff + j * 1024);
    __builtin_amdgcn_s_setprio(1);
#pragma unroll
    for (int i = 0; i < 4; ++i)
#pragma unroll
      for (int j = 0; j < 4; ++j)
        acc[i][j] = __builtin_amdgcn_mfma_f32_16x16x32_f16(af[i], bg[j], acc[i][j], 0, 0, 0);
    __builtin_amdgcn_s_setprio(0);
  }
#undef STAGE

  // -------- epilogue: j-min -> one shfl_xor(8) -> LDS planes -> scan -------
  float wnv[4];
#pragma unroll
  for (int n = 0; n < 4; ++n) wnv[n] = wn2[col0 + wc * 64 + n * 16 + lA];
  float* pm = (float*)smem;
  float* ps = (float*)(smem + 16896);
  int*   pc = (int*)(smem + 33792);
  __syncthreads();

#pragma unroll
  for (int i = 0; i < 4; ++i) {
#pragma unroll
    for (int qq = 0; qq < 4; ++qq) {
      float m = FLT_MAX, s = FLT_MAX; int c = 0;
#pragma unroll
      for (int j = 0; j < 4; ++j) {
        float d = fmaf(-2.0f, acc[i][j][qq], wnv[j]);
        int cc = wc * 64 + j * 16 + lA;
        if (d < m) { s = m; m = d; c = cc; }
        else if (d < s) s = d;
      }
      float om = __shfl_xor(m, 8, 64);
      float os = __shfl_xor(s, 8, 64);
      int   oc = __shfl_xor(c, 8, 64);
      float ns = fminf(fminf(s, os), fmaxf(m, om));
      if (om < m || (om == m && oc < c)) { m = om; c = oc; }
      s = ns;
      if ((l & 8) == 0) {
        int row = wr * 64 + i * 16 + (l >> 4) * 4 + qq;
        int w33 = row * 33 + wc * 8 + (l & 7);
        pm[w33] = m; ps[w33] = s; pc[w33] = c;
      }
    }
  }
  __syncthreads();
  {
    const int row = tid >> 2;
    const int qd  = tid & 3;
    float gm = FLT_MAX, gs = FLT_MAX; int gc = 0x7fffffff;
#pragma unroll
    for (int k = 0; k < 8; ++k) {
      int w33 = row * 33 + qd * 8 + k;
      float m = pm[w33], s = ps[w33]; int c = pc[w33];
      float ns = fminf(fminf(gs, s), fmaxf(gm, m));
      if (m < gm || (m == gm && c < gc)) { gm = m; gc = c; }
      gs = ns;
    }
#pragma unroll
    for (int msk = 1; msk <= 2; msk <<= 1) {
      float om = __shfl_xor(gm, msk, 64);
      float os = __shfl_xor(gs, msk, 64);
      int   oc = __shfl_xor(gc, msk, 64);
      float ns = fminf(fminf(gs, os), fmaxf(gm, om));
      if (om < gm || (om == gm && oc < gc)) { gm = om; gc = oc; }
      gs = ns;
    }
    if (qd == 0) {
      size_t o = (size_t)ct * BT_ + row0 + row;
      tm[o] = gm; ts[o] = gs; ti[o] = col0 + gc;
    }
  }
}

// ------- kernel 4: combine tiles, per-row threshold, bin rows by tile -------
__global__ __launch_bounds__(256) void k_combine(const float* __restrict__ tm,
                                                 const float* __restrict__ ts,
                                                 const int* __restrict__ ti,
                                                 const float* __restrict__ rl,
                                                 const int* __restrict__ wlmax,
                                                 int* __restrict__ idxf,
                                                 unsigned long long* __restrict__ rowKey,
                                                 int* __restrict__ tlist,
                                                 int* __restrict__ tcnt) {
  const int row = blockIdx.x * 256 + threadIdx.x;
  const float wlm = __int_as_float(*wlmax);
  const float thr = 2.0f * (rl[row] + wlm) + 1e-4f;
  float tmv[NTILES];
  float m = FLT_MAX, s = FLT_MAX; int bi = 0x7fffffff;
#pragma unroll
  for (int t = 0; t < NTILES; ++t) {
    size_t o = (size_t)t * BT_ + row;
    float om = tm[o], os = ts[o]; int oi = ti[o];
    tmv[t] = om;
    float nsv = fminf(fminf(s, os), fmaxf(m, om));
    if (om < m || (om == m && oi < bi)) { m = om; bi = oi; }
    s = nsv;
  }
  idxf[row] = bi;
  if (s - m <= thr) {
    rowKey[row] = ~0ULL;
    const float lim = m + thr;
#pragma unroll
    for (int t = 0; t < NTILES; ++t) {
      if (tmv[t] <= lim) {
        int p = atomicAdd(&tcnt[t], 1);
        tlist[t * BT_ + p] = row;
      }
    }
  } else {
    rowKey[row] = 0ULL;
  }
}

// ------- kernel 5: tile-binned exact fp32 refine (one thread = one code) ----
// grid = 32 tiles x 8 slices; each block's 256 threads own the tile's 256
// codes (w rows L2-resident across all rows of the tile).
__global__ __launch_bounds__(256) void k_refine(const float* __restrict__ zn,
                                                const float* __restrict__ w,
                                                const float* __restrict__ wn2,
                                                const int* __restrict__ tlist,
                                                const int* __restrict__ tcnt,
                                                unsigned long long* __restrict__ rowKey) {
  __shared__ float4 znr[64];
  const int tid = threadIdx.x;
  const int t   = blockIdx.x >> 3;
  const int sl  = blockIdx.x & 7;
  const int cnt = tcnt[t];
  const int c   = t * BN + tid;
  const float wnc = wn2[c];
  const float4* wr4 = reinterpret_cast<const float4*>(w) + (size_t)c * 64;

  for (int i = sl; i < cnt; i += 8) {
    const int row = tlist[t * BT_ + i];
    __syncthreads();
    if (tid < 64)
      znr[tid] = *(reinterpret_cast<const float4*>(zn) + (size_t)row * 64 + tid);
    __syncthreads();
    float d0 = 0.f, d1 = 0.f, d2 = 0.f, d3 = 0.f;
#pragma unroll
    for (int k4 = 0; k4 < 16; ++k4) {
      float4 a0 = znr[k4 * 4 + 0], b0 = wr4[k4 * 4 + 0];
      float4 a1 = znr[k4 * 4 + 1], b1 = wr4[k4 * 4 + 1];
      float4 a2 = znr[k4 * 4 + 2], b2 = wr4[k4 * 4 + 2];
      float4 a3 = znr[k4 * 4 + 3], b3 = wr4[k4 * 4 + 3];
      d0 = fmaf(a0.x, b0.x, d0); d0 = fmaf(a0.y, b0.y, d0);
      d0 = fmaf(a0.z, b0.z, d0); d0 = fmaf(a0.w, b0.w, d0);
      d1 = fmaf(a1.x, b1.x, d1); d1 = fmaf(a1.y, b1.y, d1);
      d1 = fmaf(a1.z, b1.z, d1); d1 = fmaf(a1.w, b1.w, d1);
      d2 = fmaf(a2.x, b2.x, d2); d2 = fmaf(a2.y, b2.y, d2);
      d2 = fmaf(a2.z, b2.z, d2); d2 = fmaf(a2.w, b2.w, d2);
      d3 = fmaf(a3.x, b3.x, d3); d3 = fmaf(a3.y, b3.y, d3);
      d3 = fmaf(a3.z, b3.z, d3); d3 = fmaf(a3.w, b3.w, d3);
    }
    float dot = (d0 + d1) + (d2 + d3);
    float d = fmaf(-2.0f, dot, wnc);
    unsigned long long key = ((unsigned long long)ford(d) << 32) | (unsigned)c;
#pragma unroll
    for (int msk = 1; msk < 64; msk <<= 1) {
      unsigned long long ok = __shfl_xor(key, msk, 64);
      key = (ok < key) ? ok : key;
    }
    if ((tid & 63) == 0) atomicMin(&rowKey[row], key);
  }
}

// ---------------- kernel 6: gather + loss partials (atomic-free) ----------------
__global__ __launch_bounds__(256) void k_gather(const float* __restrict__ zn,
                                                const float* __restrict__ w,
                                                const int* __restrict__ idxf,
                                                const unsigned long long* __restrict__ rowKey,
                                                float* __restrict__ zq,
                                                float* __restrict__ idx_out,
                                                float* __restrict__ wpart) {
  const int row  = blockIdx.x * 4 + (threadIdx.x >> 6);
  const int lane = threadIdx.x & 63;
  unsigned long long key = rowKey[row];
  const int bi = (key == 0ULL) ? idxf[row] : (int)(key & 0xFFFFFFFFu);
  float4 cv = *(reinterpret_cast<const float4*>(w)  + (size_t)bi  * 64 + lane);
  float4 zv = *(reinterpret_cast<const float4*>(zn) + (size_t)row * 64 + lane);
  *(reinterpret_cast<float4*>(zq) + (size_t)row * 64 + lane) = cv;
  float dx = cv.x - zv.x, dy = cv.y - zv.y, dz = cv.z - zv.z, dw = cv.w - zv.w;
  float s = dx * dx + dy * dy + dz * dz + dw * dw;
#pragma unroll
  for (int o = 32; o > 0; o >>= 1) s += __shfl_xor(s, o, 64);
  if (lane == 0) {
    wpart[row] = s;
    idx_out[row] = (float)bi;
  }
}

// ---------------- kernel 7: final loss reduction ----------------
__global__ __launch_bounds__(256) void k_final(const float* __restrict__ wpart,
                                               float* __restrict__ loss_out) {
  __shared__ float wsum[4];
  float s = 0.f;
  for (int i = threadIdx.x; i < BT_; i += 256) s += wpart[i];
#pragma unroll
  for (int o = 32; o > 0; o >>= 1) s += __shfl_xor(s, o, 64);
  if ((threadIdx.x & 63) == 0) wsum[threadIdx.x >> 6] = s;
  __syncthreads();
  if (threadIdx.x == 0)
    loss_out[0] = BETA_ * ((wsum[0] + wsum[1]) + (wsum[2] + wsum[3])) *
                  (1.0f / (float)(BT_ * D_));
}

extern "C" void kernel_launch(void* const* d_in, const int* in_sizes, int n_in,
                              void* d_out, int out_size, void* d_ws, size_t ws_size,
                              hipStream_t stream) {
  const float* z = (const float*)d_in[0];
  const float* w = (const float*)d_in[1];

  float* out      = (float*)d_out;
  float* zq       = out;
  float* loss_out = out + (size_t)BT_ * D_;
  float* idx_out  = loss_out + 1;

  char* wsb = (char*)d_ws;
  float*  zn      = (float*)(wsb);                           // 16 MB
  ushort* Acat    = (ushort*)(wsb + 16777216);               // 16 MB
  ushort* Bcat    = (ushort*)(wsb + 33554432);               // 8 MB
  float*  tm      = (float*)(wsb + 41943040);                // 2 MB
  float*  ts      = (float*)(wsb + 46137344);                // 2 MB (wpart reuse)
  int*    ti      = (int*)(wsb + 50331648);                  // 2 MB
  float*  wn2     = (float*)(wsb + 54525952);                // 32 KB
  float*  rl      = (float*)(wsb + 54558720);                // 64 KB
  int*    idxf    = (int*)(wsb + 54624256);                  // 64 KB
  unsigned long long* rowKey = (unsigned long long*)(wsb + 54689792);  // 128 KB
  int*    tlist   = (int*)(wsb + 54820864);                  // 2 MB
  int*    tcnt    = (int*)(wsb + 56918016);                  // 128 B
  int*    wlmax   = (int*)(wsb + 56918144);                  // 4 B
  float*  wpart   = ts;   // ts is dead after k_combine

  hipFuncSetAttribute((const void*)k_coarse,
                      hipFuncAttributeMaxDynamicSharedMemorySize, 73728);

  hipMemsetAsync(tcnt, 0, 132, stream);   // tcnt[32] + wlmax
  k_prep_z<<<BT_ / 4, 256, 0, stream>>>(z, zn, Acat, rl);
  k_prep_w<<<N_ / 4, 256, 0, stream>>>(w, wn2, Bcat, wlmax);
  k_coarse<<<(BT_ / BM) * NTILES, 512, 73728, stream>>>(Acat, Bcat, wn2, tm, ts, ti);
  k_combine<<<BT_ / 256, 256, 0, stream>>>(tm, ts, ti, rl, wlmax, idxf, rowKey, tlist, tcnt);
  k_refine<<<NTILES * 8, 256, 0, stream>>>(zn, w, wn2, tlist, tcnt, rowKey);
  k_gather<<<BT_ / 4, 256, 0, stream>>>(zn, w, idxf, rowKey, zq, idx_out, wpart);
  k_final<<<1, 256, 0, stream>>>(wpart, loss_out);
}

// Round 12
// 247.461 us; speedup vs baseline: 1.6149x; 1.4033x over previous
//
#include <hip/hip_runtime.h>
#include <float.h>
#include <math.h>

// NormEMAVectorQuantizer via split-fp16 MFMA + exact fp32 refinement.
// z (8,2048,256) f32, weight (8192,256) f32 (unit rows).
// out = [ z_q (16384*256) | loss (1) | indices (16384, as float) ]
//
// Round-12: subtile-64 pruning. Coarse epilogue's scan1 already computes
// per-(row, 64-code-subtile) coarse minima -> store to tm2[row][128] (one
// extra store). Refine: per flagged row, candidate subtiles = {tm2 <= lim};
// exact fp32 over ~64-192 codes instead of ~1000 (r11's 135us refine).
// Bound: |d_co - d_ex| <= Emax = 2*(rl + 4e-5); flag iff s-m <= 4rl+2.5e-4;
// lim = m + thr; candidate set provably contains true argmin.

#define BT_ 16384
#define D_  256
#define N_  8192
#define BETA_ 1.0f

#define BM 128
#define BN 256
#define NKT 16           // 512 / 32 K-tiles
#define NTILES 32        // N_ / BN

typedef __attribute__((ext_vector_type(8))) _Float16 f16x8;
typedef __attribute__((ext_vector_type(4))) float f32x4;

__device__ __forceinline__ void gld16(void* lds, const void* g) {
  __builtin_amdgcn_global_load_lds(
      (const __attribute__((address_space(1))) void*)g,
      (__attribute__((address_space(3))) void*)lds, 16, 0, 0);
}

__device__ __forceinline__ unsigned short f2h(float x) {
  _Float16 h = (_Float16)x;
  return __builtin_bit_cast(unsigned short, h);
}
__device__ __forceinline__ float h2f(unsigned short u) {
  return (float)__builtin_bit_cast(_Float16, u);
}
// monotone float -> uint32 (total order, handles negatives exactly)
__device__ __forceinline__ unsigned ford(float f) {
  unsigned b = __float_as_uint(f);
  return (b & 0x80000000u) ? ~b : (b | 0x80000000u);
}

// ---------------- kernel 1: normalize z, A = [zh|zh], rl = ||zl|| ------------
__global__ __launch_bounds__(256) void k_prep_z(const float* __restrict__ z,
                                                float* __restrict__ zn,
                                                ushort* __restrict__ Acat,
                                                float* __restrict__ rl) {
  const int row  = blockIdx.x * 4 + (threadIdx.x >> 6);
  const int lane = threadIdx.x & 63;
  float4 v = *(reinterpret_cast<const float4*>(z) + (size_t)row * 64 + lane);
  float s = v.x * v.x + v.y * v.y + v.z * v.z + v.w * v.w;
#pragma unroll
  for (int o = 32; o > 0; o >>= 1) s += __shfl_xor(s, o, 64);
  float dn = fmaxf(sqrtf(s), 1e-12f);
  v.x /= dn; v.y /= dn; v.z /= dn; v.w /= dn;
  *(reinterpret_cast<float4*>(zn) + (size_t)row * 64 + lane) = v;
  ushort4 h = make_ushort4(f2h(v.x), f2h(v.y), f2h(v.z), f2h(v.w));
  float lx = v.x - h2f(h.x), ly = v.y - h2f(h.y);
  float lz = v.z - h2f(h.z), lw = v.w - h2f(h.w);
  float s2 = lx * lx + ly * ly + lz * lz + lw * lw;
#pragma unroll
  for (int o = 32; o > 0; o >>= 1) s2 += __shfl_xor(s2, o, 64);
  if (lane == 0) rl[row] = sqrtf(s2);
  ushort4* A4 = reinterpret_cast<ushort4*>(Acat);
  size_t rb = (size_t)row * 128 + lane;   // 512/4 = 128 ushort4 per row
  A4[rb]      = h;    // zh
  A4[rb + 64] = h;    // zh (second copy)
}

// ---------------- kernel 2: wn2, B = [wh|wl] ----------------
__global__ __launch_bounds__(256) void k_prep_w(const float* __restrict__ w,
                                                float* __restrict__ wn2,
                                                ushort* __restrict__ Bcat) {
  const int row  = blockIdx.x * 4 + (threadIdx.x >> 6);
  const int lane = threadIdx.x & 63;
  float4 v = *(reinterpret_cast<const float4*>(w) + (size_t)row * 64 + lane);
  float s = v.x * v.x + v.y * v.y + v.z * v.z + v.w * v.w;
#pragma unroll
  for (int o = 32; o > 0; o >>= 1) s += __shfl_xor(s, o, 64);
  if (lane == 0) wn2[row] = s;
  ushort4 h  = make_ushort4(f2h(v.x), f2h(v.y), f2h(v.z), f2h(v.w));
  ushort4 lo = make_ushort4(f2h(v.x - h2f(h.x)), f2h(v.y - h2f(h.y)),
                            f2h(v.z - h2f(h.z)), f2h(v.w - h2f(h.w)));
  ushort4* B4 = reinterpret_cast<ushort4*>(Bcat);
  size_t rb = (size_t)row * 128 + lane;
  B4[rb]      = h;    // wh
  B4[rb + 64] = lo;   // wl
}

// ---------------- kernel 3: high-occupancy fp16 MFMA GEMM + tm2 -------------
__global__ __launch_bounds__(512, 4) void k_coarse(const ushort* __restrict__ Acat,
                                                   const ushort* __restrict__ Bcat,
                                                   const float* __restrict__ wn2,
                                                   float* __restrict__ tm,
                                                   float* __restrict__ ts,
                                                   int* __restrict__ ti,
                                                   float* __restrict__ tm2) {
  extern __shared__ char smem[];

  const int tid = threadIdx.x;
  const int l   = tid & 63;
  const int wv  = tid >> 6;
  const int wr  = wv >> 2;       // 0..1 -> rows wr*64
  const int wc  = wv & 3;        // 0..3 -> cols wc*64
  const int bid  = blockIdx.x;
  const int xcd  = bid & 7;
  const int q    = bid >> 3;               // 0..511
  const int chnk = q >> 5, wq = q & 31;    // 16 chunks of 32
  const int rt   = xcd * 16 + (chnk >> 3) * 8 + (wq >> 2);
  const int ct   = (chnk & 7) * 4 + (wq & 3);
  const int row0 = rt * BM;
  const int col0 = ct * BN;

  const int sgr = ((l & 3) ^ ((l >> 3) & 3)) * 16;
  const char* gsrc[3];
  unsigned    ldst[3];
#pragma unroll
  for (int s = 0; s < 3; ++s) {
    int u = wv * 3 + s;
    if (u < 8) {
      gsrc[s] = (const char*)Acat + (size_t)(row0 + u * 16 + (l >> 2)) * 1024 + sgr;
      ldst[s] = u * 1024;
    } else {
      gsrc[s] = (const char*)Bcat + (size_t)(col0 + (u - 8) * 16 + (l >> 2)) * 1024 + sgr;
      ldst[s] = 8192 + (u - 8) * 1024;
    }
  }
#define STAGE(t)                                                               \
  do {                                                                         \
    char* _b = smem + ((t) % 3) * 24576;                                       \
    _Pragma("unroll")                                                          \
    for (int s = 0; s < 3; ++s) gld16(_b + ldst[s], gsrc[s] + (size_t)(t) * 64); \
  } while (0)

  const int lA  = l & 15;
  const int gsw = (lA >> 1) & 3;
  const int gk  = (l >> 4) ^ gsw;
  const unsigned aOff = (unsigned)((wr * 64 + lA) * 64 + gk * 16);
  const unsigned bOff = (unsigned)(8192 + (wc * 64 + lA) * 64 + gk * 16);

  f32x4 acc[4][4];
#pragma unroll
  for (int i = 0; i < 4; ++i)
#pragma unroll
    for (int j = 0; j < 4; ++j) acc[i][j] = (f32x4){0.f, 0.f, 0.f, 0.f};

  STAGE(0);
  STAGE(1);

  for (int t = 0; t < NKT; ++t) {
    char* buf = smem + (t % 3) * 24576;
    if (t < NKT - 1) asm volatile("s_waitcnt vmcnt(3)" ::: "memory");
    else             asm volatile("s_waitcnt vmcnt(0)" ::: "memory");
    __builtin_amdgcn_s_barrier();
    __builtin_amdgcn_sched_barrier(0);
    if (t + 2 < NKT) STAGE(t + 2);

    f16x8 af[4], bg[4];
#pragma unroll
    for (int i = 0; i < 4; ++i)
      af[i] = *(const f16x8*)(buf + aOff + i * 1024);
#pragma unroll
    for (int j = 0; j < 4; ++j)
      bg[j] = *(const f16x8*)(buf + bOff + j * 1024);
    __builtin_amdgcn_s_setprio(1);
#pragma unroll
    for (int i = 0; i < 4; ++i)
#pragma unroll
      for (int j = 0; j < 4; ++j)
        acc[i][j] = __builtin_amdgcn_mfma_f32_16x16x32_f16(af[i], bg[j], acc[i][j], 0, 0, 0);
    __builtin_amdgcn_s_setprio(0);
  }
#undef STAGE

  // -------- epilogue: j-min -> one shfl_xor(8) -> LDS planes -> scan -------
  float wnv[4];
#pragma unroll
  for (int n = 0; n < 4; ++n) wnv[n] = wn2[col0 + wc * 64 + n * 16 + lA];
  float* pm = (float*)smem;
  float* ps = (float*)(smem + 16896);
  int*   pc = (int*)(smem + 33792);
  __syncthreads();

#pragma unroll
  for (int i = 0; i < 4; ++i) {
#pragma unroll
    for (int qq = 0; qq < 4; ++qq) {
      float m = FLT_MAX, s = FLT_MAX; int c = 0;
#pragma unroll
      for (int j = 0; j < 4; ++j) {
        float d = fmaf(-2.0f, acc[i][j][qq], wnv[j]);
        int cc = wc * 64 + j * 16 + lA;
        if (d < m) { s = m; m = d; c = cc; }
        else if (d < s) s = d;
      }
      float om = __shfl_xor(m, 8, 64);
      float os = __shfl_xor(s, 8, 64);
      int   oc = __shfl_xor(c, 8, 64);
      float ns = fminf(fminf(s, os), fmaxf(m, om));
      if (om < m || (om == m && oc < c)) { m = om; c = oc; }
      s = ns;
      if ((l & 8) == 0) {
        int row = wr * 64 + i * 16 + (l >> 4) * 4 + qq;
        int w33 = row * 33 + wc * 8 + (l & 7);
        pm[w33] = m; ps[w33] = s; pc[w33] = c;
      }
    }
  }
  __syncthreads();
  {
    const int row = tid >> 2;      // 0..127
    const int qd  = tid & 3;       // = wc slice of 64 codes
    float gm = FLT_MAX, gs = FLT_MAX; int gc = 0x7fffffff;
#pragma unroll
    for (int k = 0; k < 8; ++k) {
      int w33 = row * 33 + qd * 8 + k;
      float m = pm[w33], s = ps[w33]; int c = pc[w33];
      float ns = fminf(fminf(gs, s), fmaxf(gm, m));
      if (m < gm || (m == gm && c < gc)) { gm = m; gc = c; }
      gs = ns;
    }
    // per-(row, 64-code-subtile) coarse min for refine pruning
    tm2[(size_t)(row0 + row) * 128 + ct * 4 + qd] = gm;
#pragma unroll
    for (int msk = 1; msk <= 2; msk <<= 1) {
      float om = __shfl_xor(gm, msk, 64);
      float os = __shfl_xor(gs, msk, 64);
      int   oc = __shfl_xor(gc, msk, 64);
      float ns = fminf(fminf(gs, os), fmaxf(gm, om));
      if (om < gm || (om == gm && oc < gc)) { gm = om; gc = oc; }
      gs = ns;
    }
    if (qd == 0) {
      size_t o = (size_t)ct * BT_ + row0 + row;
      tm[o] = gm; ts[o] = gs; ti[o] = col0 + gc;
    }
  }
}

// ------- kernel 4: combine tiles, flag rows, compute lim ---------------------
__global__ __launch_bounds__(256) void k_combine(const float* __restrict__ tm,
                                                 const float* __restrict__ ts,
                                                 const int* __restrict__ ti,
                                                 const float* __restrict__ rl,
                                                 int* __restrict__ idxf,
                                                 float* __restrict__ lim,
                                                 unsigned long long* __restrict__ rowKey,
                                                 int* __restrict__ flagged,
                                                 int* __restrict__ count) {
  const int row = blockIdx.x * 256 + threadIdx.x;
  float m = FLT_MAX, s = FLT_MAX; int bi = 0x7fffffff;
#pragma unroll
  for (int t = 0; t < NTILES; ++t) {
    size_t o = (size_t)t * BT_ + row;
    float om = tm[o], os = ts[o]; int oi = ti[o];
    float nsv = fminf(fminf(s, os), fmaxf(m, om));
    if (om < m || (om == m && oi < bi)) { m = om; bi = oi; }
    s = nsv;
  }
  idxf[row] = bi;
  // Emax = 2*(rl + accum~4e-5); flag iff s-m <= 2*Emax = 4*rl + ~1.6e-4 (+margin)
  const float thr = 4.0f * rl[row] + 2.5e-4f;
  if (s - m <= thr) {
    rowKey[row] = ~0ULL;
    lim[row] = m + thr;
    int p = atomicAdd(count, 1);
    flagged[p] = row;
  } else {
    rowKey[row] = 0ULL;
  }
}

// ------- kernel 5: per-row exact refine over candidate 64-code subtiles -----
__global__ __launch_bounds__(256) void k_refine(const float* __restrict__ zn,
                                                const float* __restrict__ w,
                                                const float* __restrict__ wn2,
                                                const float* __restrict__ tm2,
                                                const float* __restrict__ lim,
                                                const int* __restrict__ flagged,
                                                const int* __restrict__ count,
                                                unsigned long long* __restrict__ rowKey) {
  __shared__ float4 znr[64];
  __shared__ int cand[128];
  __shared__ int ncand;
  const int tid = threadIdx.x;
  const int l   = tid & 63;
  const int wv  = tid >> 6;
  const int cnt = *count;
  for (int f = blockIdx.x; f < cnt; f += gridDim.x) {
    __syncthreads();   // guard LDS reuse across iterations
    const int row = flagged[f];
    if (tid == 0) ncand = 0;
    if (tid < 64)
      znr[tid] = *(reinterpret_cast<const float4*>(zn) + (size_t)row * 64 + tid);
    __syncthreads();
    const float lv = lim[row];
    if (tid < 128) {
      float t2 = tm2[(size_t)row * 128 + tid];
      if (t2 <= lv) { int p = atomicAdd(&ncand, 1); cand[p] = tid; }
    }
    __syncthreads();
    const int nc = ncand;
    unsigned long long key = ~0ULL;
    for (int i = wv; i < nc; i += 4) {
      const int g = cand[i];
      const int c = g * 64 + l;
      const float4* wr4 = reinterpret_cast<const float4*>(w) + (size_t)c * 64;
      float d0 = 0.f, d1 = 0.f, d2 = 0.f, d3 = 0.f;
#pragma unroll
      for (int k4 = 0; k4 < 16; ++k4) {
        float4 a0 = znr[k4 * 4 + 0], b0 = wr4[k4 * 4 + 0];
        float4 a1 = znr[k4 * 4 + 1], b1 = wr4[k4 * 4 + 1];
        float4 a2 = znr[k4 * 4 + 2], b2 = wr4[k4 * 4 + 2];
        float4 a3 = znr[k4 * 4 + 3], b3 = wr4[k4 * 4 + 3];
        d0 = fmaf(a0.x, b0.x, d0); d0 = fmaf(a0.y, b0.y, d0);
        d0 = fmaf(a0.z, b0.z, d0); d0 = fmaf(a0.w, b0.w, d0);
        d1 = fmaf(a1.x, b1.x, d1); d1 = fmaf(a1.y, b1.y, d1);
        d1 = fmaf(a1.z, b1.z, d1); d1 = fmaf(a1.w, b1.w, d1);
        d2 = fmaf(a2.x, b2.x, d2); d2 = fmaf(a2.y, b2.y, d2);
        d2 = fmaf(a2.z, b2.z, d2); d2 = fmaf(a2.w, b2.w, d2);
        d3 = fmaf(a3.x, b3.x, d3); d3 = fmaf(a3.y, b3.y, d3);
        d3 = fmaf(a3.z, b3.z, d3); d3 = fmaf(a3.w, b3.w, d3);
      }
      float dot = (d0 + d1) + (d2 + d3);
      float d = fmaf(-2.0f, dot, wn2[c]);
      unsigned long long k = ((unsigned long long)ford(d) << 32) | (unsigned)c;
      key = (k < key) ? k : key;
    }
#pragma unroll
    for (int msk = 1; msk < 64; msk <<= 1) {
      unsigned long long ok = __shfl_xor(key, msk, 64);
      key = (ok < key) ? ok : key;
    }
    if (l == 0 && key != ~0ULL) atomicMin(&rowKey[row], key);
  }
}

// ---------------- kernel 6: gather + loss partials (atomic-free) ----------------
__global__ __launch_bounds__(256) void k_gather(const float* __restrict__ zn,
                                                const float* __restrict__ w,
                                                const int* __restrict__ idxf,
                                                const unsigned long long* __restrict__ rowKey,
                                                float* __restrict__ zq,
                                                float* __restrict__ idx_out,
                                                float* __restrict__ wpart) {
  const int row  = blockIdx.x * 4 + (threadIdx.x >> 6);
  const int lane = threadIdx.x & 63;
  unsigned long long key = rowKey[row];
  const int bi = (key == 0ULL) ? idxf[row] : (int)(key & 0xFFFFFFFFu);
  float4 cv = *(reinterpret_cast<const float4*>(w)  + (size_t)bi  * 64 + lane);
  float4 zv = *(reinterpret_cast<const float4*>(zn) + (size_t)row * 64 + lane);
  *(reinterpret_cast<float4*>(zq) + (size_t)row * 64 + lane) = cv;
  float dx = cv.x - zv.x, dy = cv.y - zv.y, dz = cv.z - zv.z, dw = cv.w - zv.w;
  float s = dx * dx + dy * dy + dz * dz + dw * dw;
#pragma unroll
  for (int o = 32; o > 0; o >>= 1) s += __shfl_xor(s, o, 64);
  if (lane == 0) {
    wpart[row] = s;
    idx_out[row] = (float)bi;
  }
}

// ---------------- kernel 7: final loss reduction ----------------
__global__ __launch_bounds__(256) void k_final(const float* __restrict__ wpart,
                                               float* __restrict__ loss_out) {
  __shared__ float wsum[4];
  float s = 0.f;
  for (int i = threadIdx.x; i < BT_; i += 256) s += wpart[i];
#pragma unroll
  for (int o = 32; o > 0; o >>= 1) s += __shfl_xor(s, o, 64);
  if ((threadIdx.x & 63) == 0) wsum[threadIdx.x >> 6] = s;
  __syncthreads();
  if (threadIdx.x == 0)
    loss_out[0] = BETA_ * ((wsum[0] + wsum[1]) + (wsum[2] + wsum[3])) *
                  (1.0f / (float)(BT_ * D_));
}

extern "C" void kernel_launch(void* const* d_in, const int* in_sizes, int n_in,
                              void* d_out, int out_size, void* d_ws, size_t ws_size,
                              hipStream_t stream) {
  const float* z = (const float*)d_in[0];
  const float* w = (const float*)d_in[1];

  float* out      = (float*)d_out;
  float* zq       = out;
  float* loss_out = out + (size_t)BT_ * D_;
  float* idx_out  = loss_out + 1;

  char* wsb = (char*)d_ws;
  float*  zn      = (float*)(wsb);                           // 16 MB
  ushort* Acat    = (ushort*)(wsb + 16777216);               // 16 MB
  ushort* Bcat    = (ushort*)(wsb + 33554432);               // 8 MB
  float*  tm      = (float*)(wsb + 41943040);                // 2 MB
  float*  ts      = (float*)(wsb + 46137344);                // 2 MB (wpart reuse)
  int*    ti      = (int*)(wsb + 50331648);                  // 2 MB
  float*  tm2     = (float*)(wsb + 54525952);                // 8 MB
  float*  wn2     = (float*)(wsb + 62914560);                // 32 KB
  float*  rl      = (float*)(wsb + 62947328);                // 64 KB
  int*    idxf    = (int*)(wsb + 63012864);                  // 64 KB
  float*  lim     = (float*)(wsb + 63078400);                // 64 KB
  unsigned long long* rowKey = (unsigned long long*)(wsb + 63143936);  // 128 KB
  int*    flagged = (int*)(wsb + 63275008);                  // 64 KB
  int*    count   = (int*)(wsb + 63340544);                  // 4 B
  float*  wpart   = ts;   // ts is dead after k_combine

  hipFuncSetAttribute((const void*)k_coarse,
                      hipFuncAttributeMaxDynamicSharedMemorySize, 73728);

  hipMemsetAsync(count, 0, 4, stream);
  k_prep_z<<<BT_ / 4, 256, 0, stream>>>(z, zn, Acat, rl);
  k_prep_w<<<N_ / 4, 256, 0, stream>>>(w, wn2, Bcat);
  k_coarse<<<(BT_ / BM) * NTILES, 512, 73728, stream>>>(Acat, Bcat, wn2, tm, ts, ti, tm2);
  k_combine<<<BT_ / 256, 256, 0, stream>>>(tm, ts, ti, rl, idxf, lim, rowKey, flagged, count);
  k_refine<<<2048, 256, 0, stream>>>(zn, w, wn2, tm2, lim, flagged, count, rowKey);
  k_gather<<<BT_ / 4, 256, 0, stream>>>(zn, w, idxf, rowKey, zq, idx_out, wpart);
  k_final<<<1, 256, 0, stream>>>(wpart, loss_out);
}